// Round 4
// baseline (120.933 us; speedup 1.0000x reference)
//
#include <hip/hip_runtime.h>
#include <math.h>

#define NN 1024      // N
#define DIN 512      // D_IN
#define DD 128       // D
#define ZSPLIT 4     // split-K factor for the z-GEMM (folded in decode)

static constexpr long S = (long)NN * DD;   // 131072 floats per matrix
// ws layout (floats): x | 4 z-partials | u
static constexpr long X_OFF  = 0;
static constexpr long ZP_OFF = X_OFF + S;
static constexpr long U_OFF  = ZP_OFF + ZSPLIT * S;

// ---------------------------------------------------------------------------
// D1: x = inputs @ weight, written DIRECTLY (no partials, no reduce kernel).
// Blocks 0..511: 2 rows x 128 cols each. Thread (cell = t&63 -> row,colgroup;
// kq = t>>6 -> K quarter of 128). 512 FMA/thread, then 4-way LDS combine.
// Block 512: u = W2 @ w3[:128] (verified body).
__global__ __launch_bounds__(256) void gemm_x(
    const float* __restrict__ inputs, const float* __restrict__ weight,
    const float* __restrict__ W2, const float* __restrict__ w3,
    float* __restrict__ x, float* __restrict__ u) {
  if (blockIdx.x == 512) {  // u-block
    const int kq = threadIdx.x;  // 0..255
    const float4* Wr = (const float4*)&W2[(long)kq * DD];
    float uu = 0.f;
#pragma unroll 8
    for (int l = 0; l < DD / 4; ++l) {
      const float4 wv = Wr[l];
      const float4 cv = ((const float4*)w3)[l];
      uu += wv.x * cv.x + wv.y * cv.y + wv.z * cv.z + wv.w * cv.w;
    }
    u[kq] = uu;
    return;
  }

  __shared__ float4 part[256];  // 4 KB
  const int t = threadIdx.x;
  const int cg = t & 31;            // float4 column group (cols 4cg..4cg+3)
  const int rw = (t >> 5) & 1;      // row within block
  const int kq = t >> 6;            // 0..3: K quarter
  const int row = blockIdx.x * 2 + rw;
  const int k0 = kq * (DIN / 4);    // 128-wide K slice

  float4 acc = make_float4(0.f, 0.f, 0.f, 0.f);
  for (int k = k0; k < k0 + DIN / 4; k += 4) {
    const float4 av = *(const float4*)&inputs[(long)row * DIN + k];
    const float ar[4] = {av.x, av.y, av.z, av.w};
#pragma unroll
    for (int kk = 0; kk < 4; ++kk) {
      const float4 bv = *(const float4*)&weight[(long)(k + kk) * DD + 4 * cg];
      acc.x += ar[kk] * bv.x; acc.y += ar[kk] * bv.y;
      acc.z += ar[kk] * bv.z; acc.w += ar[kk] * bv.w;
    }
  }
  part[t] = acc;
  __syncthreads();
  if (kq == 0) {  // t < 64: combine 4 K-quarters, store
    const float4 p1 = part[t + 64], p2 = part[t + 128], p3 = part[t + 192];
    acc.x += p1.x + p2.x + p3.x; acc.y += p1.y + p2.y + p3.y;
    acc.z += p1.z + p2.z + p3.z; acc.w += p1.w + p2.w + p3.w;
    *(float4*)&x[(long)row * DD + 4 * cg] = acc;
  }
}

// ---------------------------------------------------------------------------
// D2: z partials = adj @ x, split-K 4 (Kc = 256). 8-row x 128-col tiles,
// grid (128, 4) = 512 blocks (2/CU). Thread: row = ty, cols 4tx..4tx+3.
__global__ __launch_bounds__(256) void gemm_z(
    const float* __restrict__ adj, const float* __restrict__ x,
    float* __restrict__ zp) {
  const int t = threadIdx.x;
  const int tx = t & 31;
  const int ty = t >> 5;                 // 0..7 = row within tile
  const int row = blockIdx.x * 8 + ty;
  const int k0 = blockIdx.y * (NN / ZSPLIT);

  float4 acc = make_float4(0.f, 0.f, 0.f, 0.f);
  for (int k = k0; k < k0 + NN / ZSPLIT; k += 4) {
    const float4 av = *(const float4*)&adj[(long)row * NN + k];
    const float ar[4] = {av.x, av.y, av.z, av.w};
#pragma unroll
    for (int kk = 0; kk < 4; ++kk) {
      const float4 bv = *(const float4*)&x[(long)(k + kk) * DD + 4 * tx];
      acc.x += ar[kk] * bv.x; acc.y += ar[kk] * bv.y;
      acc.z += ar[kk] * bv.z; acc.w += ar[kk] * bv.w;
    }
  }
  *(float4*)&zp[(long)blockIdx.y * S + (long)row * DD + 4 * tx] = acc;
}

// ---------------------------------------------------------------------------
// D3: decode + folded z-finalize + a/b. 32x64 tile, grid (16,32) = 512 blocks.
// Staging sums the 4 z-partials per needed row into LDS (j-side scaled by
// w3[128:], i-side raw; both XOR-swizzled -> conflict-free b128 reads) and
// computes a_i = relu(z_i).u[:128], b_j = relu(z_j).u[128:] via width-32
// shfl reduces. Then the verified 4x... dot loop runs entirely from LDS.
__global__ __launch_bounds__(256) void k4_decode(
    const float* __restrict__ zp, const float* __restrict__ w3,
    const float* __restrict__ u, float* __restrict__ out) {
  __shared__ float zwl[64 * DD];   // j-side, scaled   (32 KB)
  __shared__ float zil[32 * DD];   // i-side, raw      (16 KB)
  __shared__ float a_loc[32];
  __shared__ float b_loc[64];
  const int t = threadIdx.x;
  const int i0 = blockIdx.y * 32;
  const int j0 = blockIdx.x * 64;

  // ---- stage j-side (64 rows): sum partials, scale, a/b reduce ----
#pragma unroll
  for (int s = 0; s < 8; ++s) {
    const int q = s * 256 + t;
    const int r = q >> 5;                  // 0..63
    const int k4 = (q & 31) << 2;          // 0,4,...,124
    float4 sum = make_float4(0.f, 0.f, 0.f, 0.f);
#pragma unroll
    for (int p = 0; p < ZSPLIT; ++p) {
      const float4 v = *(const float4*)&zp[(long)p * S + (long)(j0 + r) * DD + k4];
      sum.x += v.x; sum.y += v.y; sum.z += v.z; sum.w += v.w;
    }
    const float4 uv = *(const float4*)&u[DD + k4];
    float bp = fmaxf(sum.x, 0.f) * uv.x + fmaxf(sum.y, 0.f) * uv.y +
               fmaxf(sum.z, 0.f) * uv.z + fmaxf(sum.w, 0.f) * uv.w;
#pragma unroll
    for (int off = 16; off > 0; off >>= 1) bp += __shfl_down(bp, off, 32);
    if ((t & 31) == 0) b_loc[r] = bp;
    const float4 cc = *(const float4*)&w3[DD + k4];
    sum.x *= cc.x; sum.y *= cc.y; sum.z *= cc.z; sum.w *= cc.w;
    *(float4*)&zwl[r * DD + (k4 ^ ((r & 7) << 2))] = sum;
  }

  // ---- stage i-side (32 rows): sum partials (raw), a reduce ----
#pragma unroll
  for (int s = 0; s < 4; ++s) {
    const int q = s * 256 + t;
    const int r = q >> 5;                  // 0..31
    const int k4 = (q & 31) << 2;
    float4 sum = make_float4(0.f, 0.f, 0.f, 0.f);
#pragma unroll
    for (int p = 0; p < ZSPLIT; ++p) {
      const float4 v = *(const float4*)&zp[(long)p * S + (long)(i0 + r) * DD + k4];
      sum.x += v.x; sum.y += v.y; sum.z += v.z; sum.w += v.w;
    }
    const float4 uv = *(const float4*)&u[k4];
    float ap = fmaxf(sum.x, 0.f) * uv.x + fmaxf(sum.y, 0.f) * uv.y +
               fmaxf(sum.z, 0.f) * uv.z + fmaxf(sum.w, 0.f) * uv.w;
#pragma unroll
    for (int off = 16; off > 0; off >>= 1) ap += __shfl_down(ap, off, 32);
    if ((t & 31) == 0) a_loc[r] = ap;
    *(float4*)&zil[r * DD + (k4 ^ ((r & 7) << 2))] = sum;
  }
  __syncthreads();

  // ---- dot loop (verified structure, both operands from LDS) ----
  const int tx = t & 15;
  const int ty = t >> 4;                   // 0..15
  float acc[2][4] = {};
  for (int k4 = 0; k4 < DD; k4 += 4) {
    float4 ar[2], bc[4];
#pragma unroll
    for (int m = 0; m < 2; ++m) {
      const int R = ty + 16 * m;
      ar[m] = *(const float4*)&zil[R * DD + (k4 ^ ((R & 7) << 2))];
    }
#pragma unroll
    for (int m = 0; m < 4; ++m) {
      const int C = tx + 16 * m;
      bc[m] = *(const float4*)&zwl[C * DD + (k4 ^ ((C & 7) << 2))];
    }
#pragma unroll
    for (int mr = 0; mr < 2; ++mr)
#pragma unroll
      for (int mc = 0; mc < 4; ++mc)
        acc[mr][mc] += ar[mr].x * bc[mc].x + ar[mr].y * bc[mc].y +
                       ar[mr].z * bc[mc].z + ar[mr].w * bc[mc].w;
  }

#pragma unroll
  for (int mr = 0; mr < 2; ++mr) {
    const int i = i0 + ty + 16 * mr;
    const float ai = a_loc[ty + 16 * mr];
#pragma unroll
    for (int mc = 0; mc < 4; ++mc) {
      const int j = j0 + tx + 16 * mc;
      const float sc = ai + b_loc[tx + 16 * mc] + acc[mr][mc];
      out[(long)i * NN + j] = 1.0f / (1.0f + __expf(-sc));
    }
  }
}

// ---------------------------------------------------------------------------
extern "C" void kernel_launch(void* const* d_in, const int* in_sizes, int n_in,
                              void* d_out, int out_size, void* d_ws, size_t ws_size,
                              hipStream_t stream) {
  (void)in_sizes; (void)n_in; (void)out_size; (void)ws_size;
  const float* inputs = (const float*)d_in[0];   // (1024, 512)
  const float* adj    = (const float*)d_in[1];   // (1024, 1024)
  const float* weight = (const float*)d_in[2];   // (512, 128)
  const float* W2     = (const float*)d_in[3];   // (256, 128)
  const float* w3     = (const float*)d_in[4];   // (256,)
  float* out = (float*)d_out;

  float* ws = (float*)d_ws;
  float* x  = ws + X_OFF;
  float* zp = ws + ZP_OFF;
  float* u  = ws + U_OFF;

  // D1: x = inputs @ weight (direct) + u   [513 blocks]
  gemm_x<<<513, 256, 0, stream>>>(inputs, weight, W2, w3, x, u);
  // D2: z partials = adj @ x (split-K 4)   [512 blocks]
  gemm_z<<<dim3(128, ZSPLIT), 256, 0, stream>>>(adj, x, zp);
  // D3: decode + z-reduce + a/b            [512 blocks]
  k4_decode<<<dim3(16, 32), 256, 0, stream>>>(zp, w3, u, out);
}